// Round 24
// baseline (83.191 us; speedup 1.0000x reference)
//
#include <hip/hip_runtime.h>

// Problem constants
#define NBATCH 8
#define NLQ    256
#define NLK    1024
#define NDQ    512
#define NDV    512
#define NH     128
#define NEGV   -1000000.0f
#define TANH_SCALE 2.8853900817779268f   // 2*log2(e)
#define LOG2E      1.4426950408889634f

using f16x8 = __attribute__((ext_vector_type(8))) _Float16;
using f16x4 = __attribute__((ext_vector_type(4))) _Float16;
using f16x2 = __attribute__((ext_vector_type(2))) _Float16;
using f32x4 = __attribute__((ext_vector_type(4))) float;

__device__ __forceinline__ float fast_exp2(float x) {
#if __has_builtin(__builtin_amdgcn_exp2f)
  return __builtin_amdgcn_exp2f(x);
#else
  return exp2f(x);
#endif
}
__device__ __forceinline__ float fast_rcp(float x) {
#if __has_builtin(__builtin_amdgcn_rcpf)
  return __builtin_amdgcn_rcpf(x);
#else
  return 1.0f / x;
#endif
}

// ---------------------------------------------------------------------------
// Prep: WT fp16 [2][128][512]; WT[s][n][k] = W_s[k][n]. 256 KB, L2-resident.
// ---------------------------------------------------------------------------
__global__ __launch_bounds__(256)
void prep_wT_kernel(const float* __restrict__ Wq, const float* __restrict__ Wk,
                    _Float16* __restrict__ wT) {
  const int idx = blockIdx.x * 256 + threadIdx.x;   // 0 .. 2*512*128-1
  const int n = idx & 127;
  const int k = (idx >> 7) & 511;
  const int s = idx >> 16;
  const float* W = s ? Wk : Wq;
  wT[((size_t)(s * NH + n)) * NDQ + k] = (_Float16)W[k * NH + n];
}

// ---------------------------------------------------------------------------
// Projections via fp16 MFMA, LDS-FREE, barrier-free.
// Wave = 16 rows x 32 cols (2 frags of 16x16), block = 4 waves (64 rows).
// Grid (160, 4): bx<32 -> Q (M=2048), else K (M=8192); by = n-quarter.
// vlen-skip: K-blocks whose 64 keys all lie >= vlen[b] return immediately.
// Epilogue: exp2(acc*2log2e); Q -> Eq fp32 row-major, K -> EkT[b][h][key].
// ---------------------------------------------------------------------------
__global__ __launch_bounds__(256)
void proj_mfma_kernel(const float* __restrict__ Q, const float* __restrict__ Kin,
                      const _Float16* __restrict__ wT, const int* __restrict__ vlen,
                      float* __restrict__ qp, float* __restrict__ ekT) {
  const int bx = blockIdx.x;
  const int nq = blockIdx.y;          // n-quarter: cols nq*32 .. nq*32+31
  const bool isQ = (bx < 32);
  const float* A = isQ ? Q : Kin;
  const int m0 = (isQ ? bx : bx - 32) * 64;
  const int sIdx = isQ ? 0 : 1;

  if (!isQ) {
    const int b = m0 >> 10;
    if ((m0 & 1023) >= vlen[b]) return;   // dead keys: never consumed unmasked
  }

  const int w = threadIdx.x >> 6, lane = threadIdx.x & 63;
  const int mrow = m0 + w * 16 + (lane & 15);
  const int kseg = (lane >> 4) * 8;

  const float* aBase = A + (size_t)mrow * NDQ + kseg;
  const _Float16* wt0 = wT + ((size_t)(sIdx * NH + nq * 32 +      (lane & 15))) * NDQ + kseg;
  const _Float16* wt1 = wT + ((size_t)(sIdx * NH + nq * 32 + 16 + (lane & 15))) * NDQ + kseg;

  f32x4 acc0 = {}, acc1 = {};
#pragma unroll 4
  for (int k0 = 0; k0 < NDQ; k0 += 32) {
    const float4 a0 = *(const float4*)&aBase[k0];
    const float4 a1 = *(const float4*)&aBase[k0 + 4];
    f16x8 af;
    af[0] = (_Float16)a0.x; af[1] = (_Float16)a0.y;
    af[2] = (_Float16)a0.z; af[3] = (_Float16)a0.w;
    af[4] = (_Float16)a1.x; af[5] = (_Float16)a1.y;
    af[6] = (_Float16)a1.z; af[7] = (_Float16)a1.w;
    const f16x8 b0 = *(const f16x8*)&wt0[k0];
    const f16x8 b1 = *(const f16x8*)&wt1[k0];
    acc0 = __builtin_amdgcn_mfma_f32_16x16x32_f16(af, b0, acc0, 0, 0, 0);
    acc1 = __builtin_amdgcn_mfma_f32_16x16x32_f16(af, b1, acc1, 0, 0, 0);
  }

  const int orow = m0 + w * 16 + (lane >> 4) * 4;   // + r
  const int col0 = nq * 32 + (lane & 15);           // frag0 col; frag1 = +16
  if (isQ) {
#pragma unroll
    for (int r = 0; r < 4; ++r) {
      qp[(size_t)(orow + r) * NH + col0]      = fast_exp2(acc0[r] * TANH_SCALE);
      qp[(size_t)(orow + r) * NH + col0 + 16] = fast_exp2(acc1[r] * TANH_SCALE);
    }
  } else {
#pragma unroll
    for (int r = 0; r < 4; ++r) {
      const int grow = orow + r;
      const int b = grow >> 10, key = grow & 1023;
      ekT[((size_t)(b * NH) + col0)      * NLK + key] = fast_exp2(acc0[r] * TANH_SCALE);
      ekT[((size_t)(b * NH) + col0 + 16) * NLK + key] = fast_exp2(acc1[r] * TANH_SCALE);
    }
  }
}

// ---------------------------------------------------------------------------
// Scores, UNFUSED (R8 structure: the 57%-VALUBusy config) + per-wave vlen
// skip. Block = 256 thr = 4 waves, NO barriers; wave w owns key segment
// seg = blockIdx.x*4+w (128 keys, float2/lane coalesced from EkT[b][h][key]);
// QR=4 q rows; grid (2,64,8) = 1024 blocks = 8/CU queue depth, so skipped
// waves retire and the scheduler refills with fresh blocks (load balance).
// Raw scores (no mask) -> sc fp32; softmax kernel applies the mask.
//   score = Wsum - 2*sum_h w*rcp(1 + Eq*Ek); Wsum cancels in softmax.
// ---------------------------------------------------------------------------
__global__ __launch_bounds__(256)
void scores_kernel(const float* __restrict__ qp, const float* __restrict__ ekT,
                   const float* __restrict__ wv, const int* __restrict__ vlen,
                   float* __restrict__ sc) {
  const int w = threadIdx.x >> 6;
  const int lane = threadIdx.x & 63;
  const int seg = blockIdx.x * 4 + w;   // key segment (128 keys), 0..7
  const int qg  = blockIdx.y;           // q group (4 rows)
  const int b   = blockIdx.z;
  const int key0 = seg * 128 + lane * 2;

  if (seg * 128 >= vlen[b]) return;     // wave-uniform skip: masked later anyway

  const float* kcol  = &ekT[(size_t)b * NH * NLK + key0];       // + h*NLK
  const float* qbase = &qp[(size_t)(b * NLQ + qg * 4) * NH];

  float2 acc[4] = {};
#pragma unroll 8
  for (int g = 0; g < 32; ++g) {
    const float4 w4 = *(const float4*)&wv[g * 4];               // uniform
    float4 q4[4];
#pragma unroll
    for (int qi = 0; qi < 4; ++qi)
      q4[qi] = *(const float4*)&qbase[qi * NH + g * 4];         // uniform
#pragma unroll
    for (int hh = 0; hh < 4; ++hh) {
      const float2 kv = *(const float2*)&kcol[(size_t)(g * 4 + hh) * NLK];
      const float wl = (hh == 0) ? w4.x : (hh == 1) ? w4.y : (hh == 2) ? w4.z : w4.w;
#pragma unroll
      for (int qi = 0; qi < 4; ++qi) {
        const float qs = (hh == 0) ? q4[qi].x : (hh == 1) ? q4[qi].y
                       : (hh == 2) ? q4[qi].z : q4[qi].w;
        acc[qi].x = fmaf(wl, fast_rcp(fmaf(qs, kv.x, 1.0f)), acc[qi].x);
        acc[qi].y = fmaf(wl, fast_rcp(fmaf(qs, kv.y, 1.0f)), acc[qi].y);
      }
    }
  }

#pragma unroll
  for (int qi = 0; qi < 4; ++qi) {
    float2 o;
    o.x = -2.0f * acc[qi].x;
    o.y = -2.0f * acc[qi].y;
    *(float2*)&sc[(size_t)(b * NLQ + qg * 4 + qi) * NLK + key0] = o;
  }
}

// ---------------------------------------------------------------------------
// Masked softmax over keys; reads fp32 scores, writes fp16 attn IN PLACE
// (row r's halfs overlay row r's own floats; all reads complete before any
// store's data is ready -> safe). fp16 row stride = 2048 halfs.
// Beyond-VL entries (possibly unwritten by skipped scores waves) are masked
// to NEGV here, so their garbage never reaches the output.
// ---------------------------------------------------------------------------
__global__ __launch_bounds__(256)
void softmax_kernel(float* __restrict__ sc, const int* __restrict__ vlen) {
  const int row = blockIdx.x * 4 + (threadIdx.x >> 6);  // 0..2047
  const int lane = threadIdx.x & 63;
  const int VL = vlen[row >> 8];
  float* base = &sc[(size_t)row * NLK];

  float s[16];
#pragma unroll
  for (int g = 0; g < 4; ++g) {
    const int k0 = (g * 64 + lane) * 4;
    const float4 v = *(const float4*)&base[k0];
    s[g * 4 + 0] = (k0 + 0 < VL) ? v.x : NEGV;
    s[g * 4 + 1] = (k0 + 1 < VL) ? v.y : NEGV;
    s[g * 4 + 2] = (k0 + 2 < VL) ? v.z : NEGV;
    s[g * 4 + 3] = (k0 + 3 < VL) ? v.w : NEGV;
  }

  float m = s[0];
#pragma unroll
  for (int t = 1; t < 16; ++t) m = fmaxf(m, s[t]);
#pragma unroll
  for (int off = 32; off > 0; off >>= 1) m = fmaxf(m, __shfl_xor(m, off));

  float p[16];
  float sum = 0.0f;
#pragma unroll
  for (int t = 0; t < 16; ++t) {
    p[t] = fast_exp2((s[t] - m) * LOG2E);
    sum += p[t];
  }
#pragma unroll
  for (int off = 32; off > 0; off >>= 1) sum += __shfl_xor(sum, off);
  const float inv = fast_rcp(sum);

  _Float16* hbase = (_Float16*)base;
#pragma unroll
  for (int g = 0; g < 4; ++g) {
    const int k0 = (g * 64 + lane) * 4;
    f16x4 h;
    h[0] = (_Float16)(p[g * 4 + 0] * inv);
    h[1] = (_Float16)(p[g * 4 + 1] * inv);
    h[2] = (_Float16)(p[g * 4 + 2] * inv);
    h[3] = (_Float16)(p[g * 4 + 3] * inv);
    *(f16x4*)&hbase[k0] = h;
  }
}

// ---------------------------------------------------------------------------
// PV via fp16 MFMA: out[b] = attn[b] (256x1024 fp16, ROW STRIDE 2048) @ V[b].
// Tile M64 x N32 -> grid (4,16,8) = 512 blocks = 2 blocks/CU.
// Block 256 thr = 4 waves; K-step 32, register prefetch. vlen-adaptive:
// attn==0 for keys>=VL (softmax wrote exact zeros there... keys in
// [VL, 1024) have p=0 after masking), K-loop stops at ceil(VL/32)*32.
// ---------------------------------------------------------------------------
__global__ __launch_bounds__(256)
void pv_mfma_kernel(const _Float16* __restrict__ attnH, const float* __restrict__ V,
                    const int* __restrict__ vlen, float* __restrict__ out) {
  const int b  = blockIdx.z;
  const int m0 = blockIdx.x * 64;
  const int n0 = blockIdx.y * 32;
  const int tid = threadIdx.x;
  const int w = tid >> 6, lane = tid & 63;
  const int kmax = (vlen[b] + 31) & ~31;   // ceil to K-step; >=32 since VL>=1

  __shared__ _Float16 aT[64][40];   // [m][k]
  __shared__ _Float16 vT[32][32];   // [n][k], swizzled

  const _Float16* aBase = attnH + (size_t)(b * NLQ + m0) * 2048;  // stride 2048
  const float*    vBase = V + (size_t)b * NLK * NDV + n0;
  float*          oBase = out + (size_t)(b * NLQ + m0) * NDV + n0;

  const int ar = tid >> 2;               // 0..63
  const int ak = (tid & 3) * 8;          // 0,8,16,24
  const int vk = tid >> 3;               // 0..31 (k within tile)
  const int vn = (tid & 7) * 4;          // 0..28 (n within tile)
  const int vswz = ((vn >> 2) & 3) << 3;

  const int am  = w * 16 + (lane & 15);
  const int akf = (lane >> 4) * 8;
  const int bn  = lane & 15;
  const int bks = akf ^ (((bn >> 2) & 3) << 3);

  f32x4 acc0 = {}, acc1 = {};

  // prologue: prefetch tile 0 into registers
  f16x8 aReg = *(const f16x8*)&aBase[(size_t)ar * 2048 + ak];
  float4 vReg = *(const float4*)&vBase[(size_t)vk * NDV + vn];

  for (int k0 = 0; k0 < kmax; k0 += 32) {
    __syncthreads();   // previous tile's LDS reads complete
    *(f16x8*)&aT[ar][ak] = aReg;
    {
      const int ks = vk ^ vswz;
      vT[vn + 0][ks] = (_Float16)vReg.x;
      vT[vn + 1][ks] = (_Float16)vReg.y;
      vT[vn + 2][ks] = (_Float16)vReg.z;
      vT[vn + 3][ks] = (_Float16)vReg.w;
    }
    __syncthreads();

    // prefetch NEXT tile while current MFMAs run
    if (k0 + 32 < kmax) {
      aReg = *(const f16x8*)&aBase[(size_t)ar * 2048 + k0 + 32 + ak];
      vReg = *(const float4*)&vBase[(size_t)(k0 + 32 + vk) * NDV + vn];
    }

    const f16x8 af = *(const f16x8*)&aT[am][akf];
    const f16x8 bf0 = *(const f16x8*)&vT[ 0 + bn][bks];
    const f16x8 bf1 = *(const f16x8*)&vT[16 + bn][bks];
    acc0 = __builtin_amdgcn_mfma_f32_16x16x32_f16(af, bf0, acc0, 0, 0, 0);
    acc1 = __builtin_amdgcn_mfma_f32_16x16x32_f16(af, bf1, acc1, 0, 0, 0);
  }

  const int orow = w * 16 + (lane >> 4) * 4;
  const int ocol = lane & 15;
#pragma unroll
  for (int r = 0; r < 4; ++r) {
    oBase[(size_t)(orow + r) * NDV + ocol +  0] = acc0[r];
    oBase[(size_t)(orow + r) * NDV + ocol + 16] = acc1[r];
  }
}

// ---------------------------------------------------------------------------
extern "C" void kernel_launch(void* const* d_in, const int* in_sizes, int n_in,
                              void* d_out, int out_size, void* d_ws, size_t ws_size,
                              hipStream_t stream) {
  const float* Q    = (const float*)d_in[0];
  const float* Kin  = (const float*)d_in[1];
  const float* V    = (const float*)d_in[2];
  const int*   vlen = (const int*)d_in[3];
  const float* Wq   = (const float*)d_in[4];
  const float* Wk   = (const float*)d_in[5];
  const float* wv   = (const float*)d_in[6];
  float* out = (float*)d_out;

  float* qp  = (float*)d_ws;                    // Eq: 2048*128 row-major
  float* ekT = qp + NBATCH * NLQ * NH;          // EkT: 8*128*1024
  float* sc  = ekT + NBATCH * NH * NLK;         // scores fp32 -> attn fp16 in place
  _Float16* wT = (_Float16*)(sc + (size_t)NBATCH * NLQ * NLK);  // 2*128*512 fp16

  hipLaunchKernelGGL(prep_wT_kernel, dim3(2 * NDQ * NH / 256), dim3(256), 0, stream,
                     Wq, Wk, wT);
  hipLaunchKernelGGL(proj_mfma_kernel, dim3(160, 4), dim3(256), 0, stream,
                     Q, Kin, wT, vlen, qp, ekT);
  hipLaunchKernelGGL(scores_kernel, dim3(2, 64, NBATCH), dim3(256), 0, stream,
                     qp, ekT, wv, vlen, sc);
  hipLaunchKernelGGL(softmax_kernel, dim3(NBATCH * NLQ / 4), dim3(256), 0, stream,
                     sc, vlen);
  hipLaunchKernelGGL(pv_mfma_kernel, dim3(NLQ / 64, NDV / 32, NBATCH), dim3(256), 0, stream,
                     (const _Float16*)sc, V, vlen, out);
}

// Round 25
// 73.996 us; speedup vs baseline: 1.1243x; 1.1243x over previous
//
#include <hip/hip_runtime.h>

// Problem constants
#define NBATCH 8
#define NLQ    256
#define NLK    1024
#define NDQ    512
#define NDV    512
#define NH     128
#define NEGV   -1000000.0f
#define TANH_SCALE 2.8853900817779268f   // 2*log2(e)
#define LOG2E      1.4426950408889634f

using f16x8 = __attribute__((ext_vector_type(8))) _Float16;
using f16x4 = __attribute__((ext_vector_type(4))) _Float16;
using f16x2 = __attribute__((ext_vector_type(2))) _Float16;
using f32x4 = __attribute__((ext_vector_type(4))) float;

__device__ __forceinline__ float fast_exp2(float x) {
#if __has_builtin(__builtin_amdgcn_exp2f)
  return __builtin_amdgcn_exp2f(x);
#else
  return exp2f(x);
#endif
}
__device__ __forceinline__ float fast_rcp(float x) {
#if __has_builtin(__builtin_amdgcn_rcpf)
  return __builtin_amdgcn_rcpf(x);
#else
  return 1.0f / x;
#endif
}

// ---------------------------------------------------------------------------
// Prep: WT fp16 [2][128][512]; WT[s][n][k] = W_s[k][n]. 256 KB, L2-resident.
// ---------------------------------------------------------------------------
__global__ __launch_bounds__(256)
void prep_wT_kernel(const float* __restrict__ Wq, const float* __restrict__ Wk,
                    _Float16* __restrict__ wT) {
  const int idx = blockIdx.x * 256 + threadIdx.x;   // 0 .. 2*512*128-1
  const int n = idx & 127;
  const int k = (idx >> 7) & 511;
  const int s = idx >> 16;
  const float* W = s ? Wk : Wq;
  wT[((size_t)(s * NH + n)) * NDQ + k] = (_Float16)W[k * NH + n];
}

// ---------------------------------------------------------------------------
// Projections via fp16 MFMA, LDS-FREE, barrier-free.
// Wave = 16 rows x 32 cols (2 frags of 16x16), block = 4 waves (64 rows).
// Grid (160, 4): bx<32 -> Q (M=2048), else K (M=8192); by = n-quarter.
// vlen-skip: K-blocks whose 64 keys all lie >= vlen[b] return immediately.
// Epilogue: exp2(acc*2log2e); Q -> Eq fp32 row-major, K -> EkT[b][h][key].
// ---------------------------------------------------------------------------
__global__ __launch_bounds__(256)
void proj_mfma_kernel(const float* __restrict__ Q, const float* __restrict__ Kin,
                      const _Float16* __restrict__ wT, const int* __restrict__ vlen,
                      float* __restrict__ qp, float* __restrict__ ekT) {
  const int bx = blockIdx.x;
  const int nq = blockIdx.y;          // n-quarter: cols nq*32 .. nq*32+31
  const bool isQ = (bx < 32);
  const float* A = isQ ? Q : Kin;
  const int m0 = (isQ ? bx : bx - 32) * 64;
  const int sIdx = isQ ? 0 : 1;

  if (!isQ) {
    const int b = m0 >> 10;
    if ((m0 & 1023) >= vlen[b]) return;   // dead keys: never consumed unmasked
  }

  const int w = threadIdx.x >> 6, lane = threadIdx.x & 63;
  const int mrow = m0 + w * 16 + (lane & 15);
  const int kseg = (lane >> 4) * 8;

  const float* aBase = A + (size_t)mrow * NDQ + kseg;
  const _Float16* wt0 = wT + ((size_t)(sIdx * NH + nq * 32 +      (lane & 15))) * NDQ + kseg;
  const _Float16* wt1 = wT + ((size_t)(sIdx * NH + nq * 32 + 16 + (lane & 15))) * NDQ + kseg;

  f32x4 acc0 = {}, acc1 = {};
#pragma unroll 4
  for (int k0 = 0; k0 < NDQ; k0 += 32) {
    const float4 a0 = *(const float4*)&aBase[k0];
    const float4 a1 = *(const float4*)&aBase[k0 + 4];
    f16x8 af;
    af[0] = (_Float16)a0.x; af[1] = (_Float16)a0.y;
    af[2] = (_Float16)a0.z; af[3] = (_Float16)a0.w;
    af[4] = (_Float16)a1.x; af[5] = (_Float16)a1.y;
    af[6] = (_Float16)a1.z; af[7] = (_Float16)a1.w;
    const f16x8 b0 = *(const f16x8*)&wt0[k0];
    const f16x8 b1 = *(const f16x8*)&wt1[k0];
    acc0 = __builtin_amdgcn_mfma_f32_16x16x32_f16(af, b0, acc0, 0, 0, 0);
    acc1 = __builtin_amdgcn_mfma_f32_16x16x32_f16(af, b1, acc1, 0, 0, 0);
  }

  const int orow = m0 + w * 16 + (lane >> 4) * 4;   // + r
  const int col0 = nq * 32 + (lane & 15);           // frag0 col; frag1 = +16
  if (isQ) {
#pragma unroll
    for (int r = 0; r < 4; ++r) {
      qp[(size_t)(orow + r) * NH + col0]      = fast_exp2(acc0[r] * TANH_SCALE);
      qp[(size_t)(orow + r) * NH + col0 + 16] = fast_exp2(acc1[r] * TANH_SCALE);
    }
  } else {
#pragma unroll
    for (int r = 0; r < 4; ++r) {
      const int grow = orow + r;
      const int b = grow >> 10, key = grow & 1023;
      ekT[((size_t)(b * NH) + col0)      * NLK + key] = fast_exp2(acc0[r] * TANH_SCALE);
      ekT[((size_t)(b * NH) + col0 + 16) * NLK + key] = fast_exp2(acc1[r] * TANH_SCALE);
    }
  }
}

// ---------------------------------------------------------------------------
// FUSED scores + masked softmax -> fp16 attn (best measured: R18/R23).
// Block = 512 thr = 8 waves = all 1024 keys (in-block softmax); QR=4;
// grid (64, NBATCH). Per-wave vlen skip. Ping-pong kv register pipeline
// (kvA/kvB alternating, 8 loads in flight, zero copy-moves). Coalesced
// float2 loads from EkT[b][h][key]; q/w wave-uniform -> scalar loads.
//   score = Wsum - 2*sum_h w*rcp(1 + Eq*Ek); Wsum cancels in softmax.
// ---------------------------------------------------------------------------
__global__ __launch_bounds__(512)
void scores_softmax_kernel(const float* __restrict__ qp, const float* __restrict__ ekT,
                           const float* __restrict__ wv, const int* __restrict__ vlen,
                           _Float16* __restrict__ attnH) {
  const int qg = blockIdx.x;            // q group (4 rows), 0..63
  const int b  = blockIdx.y;            // batch
  const int w = threadIdx.x >> 6;       // 0..7 -> key segment of 128
  const int lane = threadIdx.x & 63;
  const int key0 = w * 128 + lane * 2;

  __shared__ float redm[8][4];
  __shared__ float reds[8][4];

  const float* kcol  = &ekT[(size_t)b * NH * NLK + key0];       // + h*NLK
  const float* qbase = &qp[(size_t)(b * NLQ + qg * 4) * NH];
  const int VL = vlen[b];

  float2 acc[4] = {};
  if (w * 128 < VL) {                   // wave-uniform: skip fully-masked segments
    float2 kvA[4], kvB[4];
#pragma unroll
    for (int hh = 0; hh < 4; ++hh)
      kvA[hh] = *(const float2*)&kcol[(size_t)hh * NLK];

#pragma unroll
    for (int g = 0; g < 32; g += 2) {
      // stage B: load g+1's kv while g's math runs
#pragma unroll
      for (int hh = 0; hh < 4; ++hh)
        kvB[hh] = *(const float2*)&kcol[(size_t)((g + 1) * 4 + hh) * NLK];

      {
        const float4 w4 = *(const float4*)&wv[g * 4];               // uniform
        float4 q4[4];
#pragma unroll
        for (int qi = 0; qi < 4; ++qi)
          q4[qi] = *(const float4*)&qbase[qi * NH + g * 4];         // uniform
#pragma unroll
        for (int hh = 0; hh < 4; ++hh) {
          const float2 kv = kvA[hh];
          const float wl = (hh == 0) ? w4.x : (hh == 1) ? w4.y : (hh == 2) ? w4.z : w4.w;
#pragma unroll
          for (int qi = 0; qi < 4; ++qi) {
            const float qs = (hh == 0) ? q4[qi].x : (hh == 1) ? q4[qi].y
                           : (hh == 2) ? q4[qi].z : q4[qi].w;
            acc[qi].x = fmaf(wl, fast_rcp(fmaf(qs, kv.x, 1.0f)), acc[qi].x);
            acc[qi].y = fmaf(wl, fast_rcp(fmaf(qs, kv.y, 1.0f)), acc[qi].y);
          }
        }
      }

      // stage A: load g+2's kv while g+1's math runs
      if (g + 2 < 32) {
#pragma unroll
        for (int hh = 0; hh < 4; ++hh)
          kvA[hh] = *(const float2*)&kcol[(size_t)((g + 2) * 4 + hh) * NLK];
      }

      {
        const float4 w4 = *(const float4*)&wv[(g + 1) * 4];         // uniform
        float4 q4[4];
#pragma unroll
        for (int qi = 0; qi < 4; ++qi)
          q4[qi] = *(const float4*)&qbase[qi * NH + (g + 1) * 4];   // uniform
#pragma unroll
        for (int hh = 0; hh < 4; ++hh) {
          const float2 kv = kvB[hh];
          const float wl = (hh == 0) ? w4.x : (hh == 1) ? w4.y : (hh == 2) ? w4.z : w4.w;
#pragma unroll
          for (int qi = 0; qi < 4; ++qi) {
            const float qs = (hh == 0) ? q4[qi].x : (hh == 1) ? q4[qi].y
                           : (hh == 2) ? q4[qi].z : q4[qi].w;
            acc[qi].x = fmaf(wl, fast_rcp(fmaf(qs, kv.x, 1.0f)), acc[qi].x);
            acc[qi].y = fmaf(wl, fast_rcp(fmaf(qs, kv.y, 1.0f)), acc[qi].y);
          }
        }
      }
    }
  }

  // finalize scores with mask
  float2 s[4];
#pragma unroll
  for (int qi = 0; qi < 4; ++qi) {
    s[qi].x = (key0 + 0 < VL) ? -2.0f * acc[qi].x : NEGV;
    s[qi].y = (key0 + 1 < VL) ? -2.0f * acc[qi].y : NEGV;
  }

  // wave-level max per q-row, then cross-wave via LDS
#pragma unroll
  for (int qi = 0; qi < 4; ++qi) {
    float m = fmaxf(s[qi].x, s[qi].y);
#pragma unroll
    for (int off = 32; off > 0; off >>= 1) m = fmaxf(m, __shfl_xor(m, off));
    if (lane == 0) redm[w][qi] = m;
  }
  __syncthreads();
  float mg[4];
#pragma unroll
  for (int qi = 0; qi < 4; ++qi) {
    float m = redm[0][qi];
#pragma unroll
    for (int ww = 1; ww < 8; ++ww) m = fmaxf(m, redm[ww][qi]);
    mg[qi] = m;
  }

  // exp + wave sum + cross-wave sum
  float2 p[4];
#pragma unroll
  for (int qi = 0; qi < 4; ++qi) {
    p[qi].x = fast_exp2((s[qi].x - mg[qi]) * LOG2E);
    p[qi].y = fast_exp2((s[qi].y - mg[qi]) * LOG2E);
    float sum = p[qi].x + p[qi].y;
#pragma unroll
    for (int off = 32; off > 0; off >>= 1) sum += __shfl_xor(sum, off);
    if (lane == 0) reds[w][qi] = sum;
  }
  __syncthreads();

#pragma unroll
  for (int qi = 0; qi < 4; ++qi) {
    float tot = reds[0][qi];
#pragma unroll
    for (int ww = 1; ww < 8; ++ww) tot += reds[ww][qi];
    const float inv = fast_rcp(tot);
    f16x2 h;
    h[0] = (_Float16)(p[qi].x * inv);
    h[1] = (_Float16)(p[qi].y * inv);
    *(f16x2*)&attnH[(size_t)(b * NLQ + qg * 4 + qi) * NLK + key0] = h;
  }
}

// ---------------------------------------------------------------------------
// PV via fp16 MFMA: out[b] = attn[b] (256x1024 fp16) @ V[b].
// Tile M64 x N32 -> grid (4,16,8) = 512 blocks = 2 blocks/CU.
// Block 256 thr = 4 waves; K-step 32, register prefetch. vlen-adaptive:
// attn==0 for keys>=VL, K-loop stops at ceil(VL/32)*32.
// ---------------------------------------------------------------------------
__global__ __launch_bounds__(256)
void pv_mfma_kernel(const _Float16* __restrict__ attnH, const float* __restrict__ V,
                    const int* __restrict__ vlen, float* __restrict__ out) {
  const int b  = blockIdx.z;
  const int m0 = blockIdx.x * 64;
  const int n0 = blockIdx.y * 32;
  const int tid = threadIdx.x;
  const int w = tid >> 6, lane = tid & 63;
  const int kmax = (vlen[b] + 31) & ~31;   // ceil to K-step; >=32 since VL>=1

  __shared__ _Float16 aT[64][40];   // [m][k]
  __shared__ _Float16 vT[32][32];   // [n][k], swizzled

  const _Float16* aBase = attnH + (size_t)(b * NLQ + m0) * NLK;
  const float*    vBase = V + (size_t)b * NLK * NDV + n0;
  float*          oBase = out + (size_t)(b * NLQ + m0) * NDV + n0;

  const int ar = tid >> 2;               // 0..63
  const int ak = (tid & 3) * 8;          // 0,8,16,24
  const int vk = tid >> 3;               // 0..31 (k within tile)
  const int vn = (tid & 7) * 4;          // 0..28 (n within tile)
  const int vswz = ((vn >> 2) & 3) << 3;

  const int am  = w * 16 + (lane & 15);
  const int akf = (lane >> 4) * 8;
  const int bn  = lane & 15;
  const int bks = akf ^ (((bn >> 2) & 3) << 3);

  f32x4 acc0 = {}, acc1 = {};

  // prologue: prefetch tile 0 into registers
  f16x8 aReg = *(const f16x8*)&aBase[(size_t)ar * NLK + ak];
  float4 vReg = *(const float4*)&vBase[(size_t)vk * NDV + vn];

  for (int k0 = 0; k0 < kmax; k0 += 32) {
    __syncthreads();   // previous tile's LDS reads complete
    *(f16x8*)&aT[ar][ak] = aReg;
    {
      const int ks = vk ^ vswz;
      vT[vn + 0][ks] = (_Float16)vReg.x;
      vT[vn + 1][ks] = (_Float16)vReg.y;
      vT[vn + 2][ks] = (_Float16)vReg.z;
      vT[vn + 3][ks] = (_Float16)vReg.w;
    }
    __syncthreads();

    // prefetch NEXT tile while current MFMAs run
    if (k0 + 32 < kmax) {
      aReg = *(const f16x8*)&aBase[(size_t)ar * NLK + k0 + 32 + ak];
      vReg = *(const float4*)&vBase[(size_t)(k0 + 32 + vk) * NDV + vn];
    }

    const f16x8 af = *(const f16x8*)&aT[am][akf];
    const f16x8 bf0 = *(const f16x8*)&vT[ 0 + bn][bks];
    const f16x8 bf1 = *(const f16x8*)&vT[16 + bn][bks];
    acc0 = __builtin_amdgcn_mfma_f32_16x16x32_f16(af, bf0, acc0, 0, 0, 0);
    acc1 = __builtin_amdgcn_mfma_f32_16x16x32_f16(af, bf1, acc1, 0, 0, 0);
  }

  const int orow = w * 16 + (lane >> 4) * 4;
  const int ocol = lane & 15;
#pragma unroll
  for (int r = 0; r < 4; ++r) {
    oBase[(size_t)(orow + r) * NDV + ocol +  0] = acc0[r];
    oBase[(size_t)(orow + r) * NDV + ocol + 16] = acc1[r];
  }
}

// ---------------------------------------------------------------------------
extern "C" void kernel_launch(void* const* d_in, const int* in_sizes, int n_in,
                              void* d_out, int out_size, void* d_ws, size_t ws_size,
                              hipStream_t stream) {
  const float* Q    = (const float*)d_in[0];
  const float* Kin  = (const float*)d_in[1];
  const float* V    = (const float*)d_in[2];
  const int*   vlen = (const int*)d_in[3];
  const float* Wq   = (const float*)d_in[4];
  const float* Wk   = (const float*)d_in[5];
  const float* wv   = (const float*)d_in[6];
  float* out = (float*)d_out;

  float* qp  = (float*)d_ws;                    // Eq: 2048*128 row-major
  float* ekT = qp + NBATCH * NLQ * NH;          // EkT: 8*128*1024
  _Float16* attnH = (_Float16*)(ekT + NBATCH * NH * NLK);       // 8*256*1024 fp16
  _Float16* wT = attnH + (size_t)NBATCH * NLQ * NLK;            // 2*128*512 fp16

  hipLaunchKernelGGL(prep_wT_kernel, dim3(2 * NDQ * NH / 256), dim3(256), 0, stream,
                     Wq, Wk, wT);
  hipLaunchKernelGGL(proj_mfma_kernel, dim3(160, 4), dim3(256), 0, stream,
                     Q, Kin, wT, vlen, qp, ekT);
  hipLaunchKernelGGL(scores_softmax_kernel, dim3(64, NBATCH), dim3(512), 0, stream,
                     qp, ekT, wv, vlen, attnH);
  hipLaunchKernelGGL(pv_mfma_kernel, dim3(NLQ / 64, NDV / 32, NBATCH), dim3(256), 0, stream,
                     attnH, V, vlen, out);
}